// Round 1
// baseline (1766.708 us; speedup 1.0000x reference)
//
#include <hip/hip_runtime.h>
#include <hip/hip_bf16.h>

#define EPS 1e-5f

static constexpr int Bv = 64, Tv = 512, Vv = 17, Hv = 128;
static constexpr int Nv = Bv * Tv;                 // 32768
static constexpr int CHv = Hv * Vv;                // 2176
static constexpr long ZBv = (long)CHv * Tv;        // 1114112 elems per batch

// workspace layout (bytes)
static constexpr size_t OFF_Z  = 0;
static constexpr size_t SZ_Z   = (size_t)Bv * (size_t)ZBv * 2;   // 142,606,336
static constexpr size_t OFF_WT = OFF_Z + SZ_Z;
static constexpr size_t SZ_WT  = (size_t)6528 * 128 * 4;         // 3,342,336
static constexpr size_t OFF_CP = OFF_WT + SZ_WT;
static constexpr size_t SZ_CP  = (size_t)Bv * Hv * Tv * 4;       // 16,777,216
static constexpr size_t OFF_ST = OFF_CP + SZ_CP;
// stats region (floats), 16-way spread accumulators:
//   s1sp[16*64]=0..1023, ss1sp=1024..2047, s2sp[16*128]=2048..4095, ss2sp=4096..6143,
//   s3sp=6144..8191, ss3sp=8192..10239,
//   sc1=10240, sh1=10304, sc2=10368, sh2=10496, sc3=10624, sh3=10752  (end 10880)

__global__ __launch_bounds__(256) void k_wt_transpose(const float* __restrict__ wt,
                                                      float* __restrict__ wt_t) {
    int e = blockIdx.x * 256 + threadIdx.x;   // e = (c*3+k)*128 + o
    if (e >= 6528 * 128) return;
    int o = e & 127, ck = e >> 7;
    wt_t[e] = wt[(size_t)o * 6528 + ck];
}

__global__ __launch_bounds__(256) void k_stats1(const float* __restrict__ x,
                                                const float* __restrict__ adj,
                                                const float* __restrict__ w1,
                                                const float* __restrict__ b1,
                                                float* __restrict__ st) {
    __shared__ float adj_s[289];
    __shared__ float xs[32 * 34];
    __shared__ float mix[32 * 34];
    __shared__ float red[256], red2[256];
    int tid = threadIdx.x;
    int n0 = blockIdx.x * 32;
    for (int i = tid; i < 289; i += 256) adj_s[i] = adj[i];
    for (int i = tid; i < 1088; i += 256) xs[i] = x[(size_t)n0 * 34 + i];
    __syncthreads();
    for (int e = tid; e < 1088; e += 256) {
        int n = e / 34, r = e % 34;
        int w = r >> 1, c = r & 1;
        float acc = 0.f;
        for (int v = 0; v < 17; ++v) acc += xs[n * 34 + v * 2 + c] * adj_s[v * 17 + w];
        mix[n * 34 + w * 2 + c] = acc;
    }
    __syncthreads();
    int o = tid & 63, g = tid >> 6;
    float w0 = w1[o * 2], w1v = w1[o * 2 + 1], bb = b1[o];
    float s = 0.f, s2 = 0.f;
    for (int n = g; n < 32; n += 4)
        for (int v = 0; v < 17; ++v) {
            float a = mix[n * 34 + v * 2] * w0 + mix[n * 34 + v * 2 + 1] * w1v + bb;
            s += a; s2 += a * a;
        }
    red[tid] = s; red2[tid] = s2;
    __syncthreads();
    if (tid < 64) {
        float S  = red[tid] + red[tid + 64] + red[tid + 128] + red[tid + 192];
        float S2 = red2[tid] + red2[tid + 64] + red2[tid + 128] + red2[tid + 192];
        int slot = blockIdx.x & 15;
        atomicAdd(&st[slot * 64 + o], S);
        atomicAdd(&st[1024 + slot * 64 + o], S2);
    }
}

__global__ void k_finalize(const float* __restrict__ sums, const float* __restrict__ sumsq,
                           const float* __restrict__ gamma, const float* __restrict__ beta,
                           float* __restrict__ scale, float* __restrict__ shift,
                           int count, float inv_denom) {
    int o = threadIdx.x;
    if (o >= count) return;
    float S = 0.f, Q = 0.f;
    for (int j = 0; j < 16; ++j) { S += sums[j * count + o]; Q += sumsq[j * count + o]; }
    float m = S * inv_denom;
    float var = Q * inv_denom - m * m;
    float rstd = rsqrtf(var + EPS);
    float sc = rstd * gamma[o];
    scale[o] = sc;
    shift[o] = beta[o] - m * sc;
}

// processes one (b, pair of t). Writes pre-BN2 block-2 output in conv layout (bf16).
__global__ __launch_bounds__(256) void k_gcn(const float* __restrict__ x,
                                             const float* __restrict__ adj,
                                             const float* __restrict__ w1,
                                             const float* __restrict__ b1,
                                             const float* __restrict__ sc1,
                                             const float* __restrict__ sh1,
                                             const float* __restrict__ w2,
                                             const float* __restrict__ b2,
                                             float* __restrict__ st,
                                             __hip_bfloat16* __restrict__ zpre) {
    __shared__ float adj_s[289];
    __shared__ float xs[68];
    __shared__ float mix1[68];
    __shared__ float h1[34 * 65];    // [nv][c] padded; later aliased as bf16 a2[128][34]
    __shared__ float mix2[40 * 65];  // [nv][c] padded (rows 34..39 zero)
    __shared__ float w2s[128 * 65];  // [o][c] padded
    __shared__ float redS[8 * 128], redQ[8 * 128];

    int tid = threadIdx.x;
    int b = blockIdx.x >> 8;
    int t0 = (blockIdx.x & 255) * 2;

    for (int i = tid; i < 289; i += 256) adj_s[i] = adj[i];
    for (int i = tid; i < 68; i += 256) xs[i] = x[(size_t)(b * 512 + t0) * 34 + i];
    for (int i = tid; i < 8192; i += 256) { int o = i >> 6, c = i & 63; w2s[o * 65 + c] = w2[i]; }
    __syncthreads();

    // mix1 = adj-mix of x  (68 entries)
    for (int e = tid; e < 68; e += 256) {
        int n = e / 34, r = e % 34, w = r >> 1, c = r & 1;
        float acc = 0.f;
        for (int v = 0; v < 17; ++v) acc += xs[n * 34 + v * 2 + c] * adj_s[v * 17 + w];
        mix1[n * 34 + w * 2 + c] = acc;
    }
    __syncthreads();

    // h1 = relu(BN1(mix1 @ w1^T + b1))   (34 x 64)
    for (int e = tid; e < 34 * 64; e += 256) {
        int nv = e >> 6, o = e & 63;
        int n = nv / 17, v = nv - n * 17;
        float a = mix1[n * 34 + v * 2] * w1[o * 2] + mix1[n * 34 + v * 2 + 1] * w1[o * 2 + 1] + b1[o];
        a = a * sc1[o] + sh1[o];
        h1[nv * 65 + o] = fmaxf(a, 0.f);
    }
    __syncthreads();

    // mix2 = adj-mix of h1  (34 x 64), thread = (nw, 16-c chunk)
    for (int e = tid; e < 136; e += 256) {
        int nw = e >> 2, cq = (e & 3) << 4;
        int n = nw / 17, w = nw - n * 17;
        float a[16];
#pragma unroll
        for (int i = 0; i < 16; ++i) a[i] = 0.f;
        for (int v = 0; v < 17; ++v) {
            float ad = adj_s[v * 17 + w];
            const float* hp = &h1[(n * 17 + v) * 65 + cq];
#pragma unroll
            for (int i = 0; i < 16; ++i) a[i] += ad * hp[i];
        }
        float* mp = &mix2[nw * 65 + cq];
#pragma unroll
        for (int i = 0; i < 16; ++i) mp[i] = a[i];
    }
    for (int e = tid; e < 6 * 65; e += 256) mix2[34 * 65 + e] = 0.f;   // zero pad rows
    __syncthreads();

    // a2 = mix2 @ w2^T + b2 : register blocked 4 o x 5 nv per thread
    int og = tid & 31, ng = tid >> 5;
    int obase = og << 2, nvbase = ng * 5;
    float accs[5][4];
#pragma unroll
    for (int i = 0; i < 5; ++i)
#pragma unroll
        for (int r = 0; r < 4; ++r) accs[i][r] = 0.f;
    for (int c4 = 0; c4 < 64; c4 += 4) {
        float wv[4][4];
#pragma unroll
        for (int r = 0; r < 4; ++r)
#pragma unroll
            for (int q = 0; q < 4; ++q) wv[r][q] = w2s[(obase + r) * 65 + c4 + q];
#pragma unroll
        for (int i = 0; i < 5; ++i) {
            const float* mp = &mix2[(nvbase + i) * 65 + c4];
            float m0 = mp[0], m1 = mp[1], m2 = mp[2], m3 = mp[3];
#pragma unroll
            for (int r = 0; r < 4; ++r)
                accs[i][r] += m0 * wv[r][0] + m1 * wv[r][1] + m2 * wv[r][2] + m3 * wv[r][3];
        }
    }

    __hip_bfloat16* a2h = reinterpret_cast<__hip_bfloat16*>(h1);  // [128][34]
    float b2r[4];
#pragma unroll
    for (int r = 0; r < 4; ++r) b2r[r] = b2[obase + r];
    float s[4] = {0, 0, 0, 0}, q2[4] = {0, 0, 0, 0};
#pragma unroll
    for (int i = 0; i < 5; ++i) {
        int nv = nvbase + i;
        if (nv < 34) {
#pragma unroll
            for (int r = 0; r < 4; ++r) {
                float vv = accs[i][r] + b2r[r];
                s[r] += vv; q2[r] += vv * vv;
                a2h[(obase + r) * 34 + nv] = __float2bfloat16(vv);
            }
        }
    }
#pragma unroll
    for (int r = 0; r < 4; ++r) { redS[ng * 128 + obase + r] = s[r]; redQ[ng * 128 + obase + r] = q2[r]; }
    __syncthreads();
    if (tid < 128) {
        float S = 0.f, Q = 0.f;
#pragma unroll
        for (int g = 0; g < 8; ++g) { S += redS[g * 128 + tid]; Q += redQ[g * 128 + tid]; }
        int slot = blockIdx.x & 15;
        atomicAdd(&st[2048 + slot * 128 + tid], S);
        atomicAdd(&st[4096 + slot * 128 + tid], Q);
    }

    // cooperative write of a2 (bf16 pairs) into conv layout: z[b][o*8704 + t*17 + v]
    const unsigned int* a2u32 = reinterpret_cast<const unsigned int*>(h1);
    unsigned int* zout = reinterpret_cast<unsigned int*>(zpre);
    size_t base = ((size_t)b * (size_t)ZBv + (size_t)t0 * 17) >> 1;  // uint units (both even)
    for (int e = tid; e < 128 * 17; e += 256) {
        int oo = e / 17, q = e - oo * 17;
        zout[base + (size_t)oo * 4352 + q] = a2u32[oo * 17 + q];
    }
}

__global__ __launch_bounds__(256) void k_conv(const __hip_bfloat16* __restrict__ zpre,
                                              const float* __restrict__ wt_t,
                                              const float* __restrict__ bt,
                                              const float* __restrict__ sc2,
                                              const float* __restrict__ sh2,
                                              float* __restrict__ cp,
                                              float* __restrict__ s3,
                                              float* __restrict__ ss3) {
    __shared__ float zt[16 * 68];     // [cc][ss] 66 used, stride 68
    __shared__ float wtt[48 * 128];   // [(cc*3+k)][o]
    int tid = threadIdx.x;
    int b = blockIdx.x >> 3;
    int s0 = (blockIdx.x & 7) * 64;
    int o = tid & 127, sh = tid >> 7;
    float acc[32];
#pragma unroll
    for (int j = 0; j < 32; ++j) acc[j] = 0.f;
    const size_t zbase = (size_t)b * (size_t)ZBv;

    for (int c0 = 0; c0 < 2176; c0 += 16) {
        __syncthreads();
        // stage z slab with BN2 + relu applied on read
        for (int e = tid; e < 16 * 66; e += 256) {
            int cc = e / 66, ss = e - cc * 66;
            int c = c0 + cc;
            int sAbs = s0 - 1 + ss;
            float v = 0.f;
            if (sAbs >= 0 && sAbs < 512) {
                float raw = __bfloat162float(zpre[zbase + (size_t)c * 512 + sAbs]);
                int hch = c / 17;
                float t = raw * sc2[hch] + sh2[hch];
                v = fmaxf(t, 0.f);
            }
            zt[cc * 68 + ss] = v;
        }
        // stage weights (contiguous in wt_t)
        {
            const float4* ws4 = reinterpret_cast<const float4*>(wt_t + (size_t)c0 * 3 * 128);
            float4* wtt4 = reinterpret_cast<float4*>(wtt);
            for (int e = tid; e < 1536; e += 256) wtt4[e] = ws4[e];
        }
        __syncthreads();
#pragma unroll 2
        for (int cc = 0; cc < 16; ++cc) {
            float zr[36];
            const float4* zp = reinterpret_cast<const float4*>(&zt[cc * 68 + sh * 32]);
#pragma unroll
            for (int q = 0; q < 9; ++q) {
                float4 f = zp[q];
                zr[4 * q] = f.x; zr[4 * q + 1] = f.y; zr[4 * q + 2] = f.z; zr[4 * q + 3] = f.w;
            }
            float w0 = wtt[(cc * 3 + 0) * 128 + o];
            float w1v = wtt[(cc * 3 + 1) * 128 + o];
            float w2v = wtt[(cc * 3 + 2) * 128 + o];
#pragma unroll
            for (int j = 0; j < 32; ++j)
                acc[j] += w0 * zr[j] + w1v * zr[j + 1] + w2v * zr[j + 2];
        }
    }
    // bias + write + stats
    float bb = bt[o];
    float s = 0.f, s2 = 0.f;
    float* cpp = cp + ((size_t)b * 128 + o) * 512 + s0 + sh * 32;
#pragma unroll
    for (int j = 0; j < 32; ++j) {
        float v = acc[j] + bb;
        s += v; s2 += v * v;
        acc[j] = v;
    }
    float4* cp4 = reinterpret_cast<float4*>(cpp);
#pragma unroll
    for (int q = 0; q < 8; ++q) cp4[q] = make_float4(acc[4 * q], acc[4 * q + 1], acc[4 * q + 2], acc[4 * q + 3]);
    int slot = blockIdx.x & 15;
    atomicAdd(&s3[slot * 128 + o], s);
    atomicAdd(&ss3[slot * 128 + o], s2);
}

__global__ __launch_bounds__(256) void k_out(const float* __restrict__ cp,
                                             const float* __restrict__ sc3,
                                             const float* __restrict__ sh3,
                                             float* __restrict__ out) {
    __shared__ float tile[128 * 33];
    int tid = threadIdx.x;
    int b = blockIdx.x >> 4;
    int t0 = (blockIdx.x & 15) * 32;
    for (int e = tid; e < 128 * 32; e += 256) {
        int o = e >> 5, tj = e & 31;
        tile[o * 33 + tj] = cp[((size_t)b * 128 + o) * 512 + t0 + tj];
    }
    __syncthreads();
    for (int e = tid; e < 128 * 32; e += 256) {
        int o = e & 127, th = e >> 7;
        float v = tile[o * 33 + th] * sc3[o] + sh3[o];
        out[((size_t)b * 512 + t0 + th) * 128 + o] = fmaxf(v, 0.f);
    }
}

extern "C" void kernel_launch(void* const* d_in, const int* in_sizes, int n_in,
                              void* d_out, int out_size, void* d_ws, size_t ws_size,
                              hipStream_t stream) {
    const float* x   = (const float*)d_in[0];
    const float* adj = (const float*)d_in[1];
    const float* w1  = (const float*)d_in[2];
    const float* b1  = (const float*)d_in[3];
    const float* g1  = (const float*)d_in[4];
    const float* be1 = (const float*)d_in[5];
    const float* w2  = (const float*)d_in[6];
    const float* b2  = (const float*)d_in[7];
    const float* g2  = (const float*)d_in[8];
    const float* be2 = (const float*)d_in[9];
    const float* wt  = (const float*)d_in[10];
    const float* bt  = (const float*)d_in[11];
    const float* gt  = (const float*)d_in[12];
    const float* bet = (const float*)d_in[13];
    float* out = (float*)d_out;

    char* ws = (char*)d_ws;
    __hip_bfloat16* zpre = (__hip_bfloat16*)(ws + OFF_Z);
    float* wt_t = (float*)(ws + OFF_WT);
    float* cp   = (float*)(ws + OFF_CP);
    float* st   = (float*)(ws + OFF_ST);

    // zero spread accumulators (first 10240 floats)
    hipMemsetAsync(st, 0, 10240 * sizeof(float), stream);

    k_wt_transpose<<<dim3((6528 * 128 + 255) / 256), dim3(256), 0, stream>>>(wt, wt_t);
    k_stats1<<<dim3(1024), dim3(256), 0, stream>>>(x, adj, w1, b1, st);
    k_finalize<<<dim3(1), dim3(128), 0, stream>>>(st, st + 1024, g1, be1,
                                                  st + 10240, st + 10304, 64, 1.f / 557056.f);
    k_gcn<<<dim3(16384), dim3(256), 0, stream>>>(x, adj, w1, b1,
                                                 st + 10240, st + 10304,
                                                 w2, b2, st, zpre);
    k_finalize<<<dim3(1), dim3(128), 0, stream>>>(st + 2048, st + 4096, g2, be2,
                                                  st + 10368, st + 10496, 128, 1.f / 557056.f);
    k_conv<<<dim3(512), dim3(256), 0, stream>>>(zpre, wt_t, bt,
                                                st + 10368, st + 10496,
                                                cp, st + 6144, st + 8192);
    k_finalize<<<dim3(1), dim3(128), 0, stream>>>(st + 6144, st + 8192, gt, bet,
                                                  st + 10624, st + 10752, 128, 1.f / 32768.f);
    k_out<<<dim3(1024), dim3(256), 0, stream>>>(cp, st + 10624, st + 10752, out);
}